// Round 4
// baseline (377.466 us; speedup 1.0000x reference)
//
#include <hip/hip_runtime.h>
#include <math.h>

#define T_TOK 4096
#define DM 1024
#define HID 4096
#define NEXP 8

typedef unsigned short u16;
typedef __attribute__((ext_vector_type(8))) short short8;
typedef __attribute__((ext_vector_type(4))) float f32x4;

__device__ __forceinline__ u16 f2bf(float f){
  unsigned u = __float_as_uint(f);
  u += 0x7FFF + ((u >> 16) & 1);
  return (u16)(u >> 16);
}

// ---- workspace layout (byte offsets) ----
#define GATE_OFF   0u          // float[4096]
#define CNT_OFF    16384u      // int[8]
#define LIST_OFF   16512u      // int[8][4096]
#define PROBS_OFF  147584u     // float[4096][8]
#define XB_OFF     278656u     // bf16[4096][1024]
#define H_OFF      8667264u    // bf16[4096][4096]
// total ~40.3 MB

__device__ __forceinline__ void glds16(const void* g, void* l){
  __builtin_amdgcn_global_load_lds((const __attribute__((address_space(1))) void*)g,
                                   (__attribute__((address_space(3))) void*)l, 16, 0, 0);
}

#define LGKM0  asm volatile("s_waitcnt lgkmcnt(0)" ::: "memory")
#define VMW8   asm volatile("s_waitcnt vmcnt(8)" ::: "memory")
#define VMW6   asm volatile("s_waitcnt vmcnt(6)" ::: "memory")
#define VMW0   asm volatile("s_waitcnt vmcnt(0)" ::: "memory")
#define SBAR() __builtin_amdgcn_s_barrier()
#define SCHED0 __builtin_amdgcn_sched_barrier(0)

__global__ void zero_cnt_kernel(int* cnt){
  if (threadIdx.x < NEXP) cnt[threadIdx.x] = 0;
}

// one wave per token: gating + routing + x->bf16 conversion
__global__ __launch_bounds__(256) void gate_kernel(
    const float* __restrict__ x, const float* __restrict__ gw,
    float* __restrict__ gateo, int* __restrict__ cnt, int* __restrict__ list,
    float* __restrict__ probs, u16* __restrict__ xb)
{
  int tid = threadIdx.x;
  int lane = tid & 63;
  int w = tid >> 6;
  int t = blockIdx.x * 4 + w;

  const float4* x4 = (const float4*)(x + (size_t)t * DM);
  const float4* g4 = (const float4*)gw;

  float acc[8] = {0,0,0,0,0,0,0,0};
  #pragma unroll
  for (int i = 0; i < 4; i++){
    int p = i * 64 + lane;
    float4 xv = x4[p];
    ushort4 pk;
    pk.x = f2bf(xv.x); pk.y = f2bf(xv.y); pk.z = f2bf(xv.z); pk.w = f2bf(xv.w);
    *(ushort4*)&xb[(size_t)t * DM + (size_t)p * 4] = pk;
    #pragma unroll
    for (int e = 0; e < NEXP; e++){
      float4 gv = g4[e * 256 + p];
      acc[e] += xv.x * gv.x + xv.y * gv.y + xv.z * gv.z + xv.w * gv.w;
    }
  }
  #pragma unroll
  for (int e = 0; e < NEXP; e++){
    #pragma unroll
    for (int off = 32; off; off >>= 1)
      acc[e] += __shfl_xor(acc[e], off);
  }
  if (lane == 0){
    float mx = acc[0];
    #pragma unroll
    for (int e = 1; e < NEXP; e++) mx = fmaxf(mx, acc[e]);
    float p[8]; float s = 0.f;
    #pragma unroll
    for (int e = 0; e < NEXP; e++){ p[e] = expf(acc[e] - mx); s += p[e]; }
    float inv = 1.f / s;
    int be = 0; float bp = p[0];
    #pragma unroll
    for (int e = 1; e < NEXP; e++){ if (p[e] > bp){ bp = p[e]; be = e; } }
    #pragma unroll
    for (int e = 0; e < NEXP; e++) probs[(size_t)t * 8 + e] = p[e] * inv;
    gateo[t] = bp * inv;
    int pos = atomicAdd(&cnt[be], 1);
    list[be * T_TOK + pos] = t;
  }
}

// deterministic aux-loss reduction, one block
__global__ __launch_bounds__(256) void aux_kernel(
    const float* __restrict__ probs, const int* __restrict__ cnt,
    float* __restrict__ aux_out)
{
  __shared__ float sm[256 * 8];
  int tid = threadIdx.x;
  float s[8] = {0,0,0,0,0,0,0,0};
  for (int i = 0; i < 16; i++){
    int t = i * 256 + tid;
    #pragma unroll
    for (int e = 0; e < 8; e++) s[e] += probs[(size_t)t * 8 + e];
  }
  #pragma unroll
  for (int e = 0; e < 8; e++) sm[tid * 8 + e] = s[e];
  __syncthreads();
  for (int st = 128; st; st >>= 1){
    if (tid < st){
      #pragma unroll
      for (int e = 0; e < 8; e++) sm[tid * 8 + e] += sm[(tid + st) * 8 + e];
    }
    __syncthreads();
  }
  if (tid == 0){
    float a = 0.f;
    #pragma unroll
    for (int e = 0; e < 8; e++){
      float f = (float)cnt[e] / (float)T_TOK;
      float P = sm[e] / (float)T_TOK;
      a += f * P;
    }
    aux_out[0] = 0.01f * (float)NEXP * a;
  }
}

// Grouped GEMM, BM=256 x BN, BK=64, 8 waves (4M x 2N), counted-vmcnt
// double-buffer. A: bf16 gathered rows via global_load_lds (pre-swizzled src).
// B: fp32 -> regs -> cvt bf16 -> swizzled ds_write (T14 split, depth-2).
// PHASE2=false: A=xb, B=w1 -> h = gelu(acc+b1) bf16
// PHASE2=true : A=h,  B=w2 -> out = gate*(acc+b2) fp32 scatter
template<int BN, int K, int BNTOT, bool PHASE2>
__global__ __launch_bounds__(512, 2) void ffn_gemm(
    const u16*  __restrict__ Aall,   // [4096][K] bf16
    const float* __restrict__ Bf,    // [E][BNTOT][K] fp32
    const float* __restrict__ bias,  // [E][BNTOT]
    const int*  __restrict__ cnt,
    const int*  __restrict__ list,   // [E][4096]
    const float* __restrict__ gate,  // [4096]
    u16*  __restrict__ hOut,
    float* __restrict__ yOut)
{
  constexpr int NT  = BNTOT / BN;
  constexpr int KS  = K / 64;
  constexpr int NFR = BN / 32;      // n-frags per wave
  constexpr int BLD = BN / 32;      // float4 B-loads per thread per K-step

  int bid = blockIdx.x;             // bid = (e*16+mt)*NT + nt  (mt pairs NT apart, NT%8==0 -> same XCD)
  int nt = bid % NT;
  int r2 = bid / NT;
  int mt = r2 & 15;
  int e  = r2 >> 4;
  int ne = cnt[e];
  int m0 = mt * 256;
  if (m0 >= ne) return;
  const int* lst = list + e * T_TOK;
  int n0 = nt * BN;

  __shared__ u16 As[2][16384];      // [256][64] swizzled
  __shared__ u16 Bs[2][BN * 64];    // [BN][64] swizzled

  int tid  = threadIdx.x;
  int lane = tid & 63;
  int w    = tid >> 6;
  int wm = w >> 1, wn = w & 1;      // 4M x 2N wave grid
  int fr = lane & 15, fq = lane >> 4;

  // ---- A staging via glds: 32 segments of 8 rows; wave w owns segs w*4..w*4+3.
  // lane l -> row seg*8+(l>>3), fetches global chunk g=(l&7)^(row&7) so that
  // LDS[row][slot] holds global chunk slot^(row&7) (both-sides swizzle).
  const u16* aS[4];
  #pragma unroll
  for (int i = 0; i < 4; i++){
    int seg = w * 4 + i;
    int r   = seg * 8 + (lane >> 3);
    int g   = (lane & 7) ^ (r & 7);
    int mrow = m0 + r; if (mrow > ne - 1) mrow = ne - 1;
    aS[i] = Aall + (size_t)lst[mrow] * K + g * 8;
  }

  // ---- B staging: thread owns float4-col c = tid&15 of rows (tid>>4)+j*32.
  const float* bS[BLD]; int bwOff[BLD];
  {
    int c = tid & 15;
    #pragma unroll
    for (int j = 0; j < BLD; j++){
      int r = (tid >> 4) + j * 32;
      bS[j] = Bf + ((size_t)e * BNTOT + n0 + r) * K + c * 4;
      bwOff[j] = r * 64 + (((c >> 1) ^ (r & 7)) * 8) + (c & 1) * 4;
    }
  }

  f32x4 acc[4][NFR];
  #pragma unroll
  for (int m = 0; m < 4; m++)
    #pragma unroll
    for (int n = 0; n < NFR; n++)
      acc[m][n] = (f32x4){0.f, 0.f, 0.f, 0.f};

  float4 bregA[BLD], bregB[BLD];

  // ---- prologue: issue tiles 0 and 1; wait tile 0; write B0.
  #pragma unroll
  for (int j = 0; j < BLD; j++) bregA[j] = *(const float4*)(bS[j]);
  #pragma unroll
  for (int i = 0; i < 4; i++){ int seg = w * 4 + i; glds16(aS[i], &As[0][seg * 512]); }
  #pragma unroll
  for (int j = 0; j < BLD; j++) bregB[j] = *(const float4*)(bS[j] + 64);
  #pragma unroll
  for (int i = 0; i < 4; i++){ int seg = w * 4 + i; glds16(aS[i] + 64, &As[1][seg * 512]); }
  if (BLD == 4) { VMW8; } else { VMW6; }
  SCHED0;
  #pragma unroll
  for (int j = 0; j < BLD; j++){
    uint2 pk;
    pk.x = (unsigned)f2bf(bregA[j].x) | ((unsigned)f2bf(bregA[j].y) << 16);
    pk.y = (unsigned)f2bf(bregA[j].z) | ((unsigned)f2bf(bregA[j].w) << 16);
    *(uint2*)&Bs[0][bwOff[j]] = pk;
  }
  LGKM0; SBAR();

#define STEP(P, T, BRI, BRW)                                                     \
  {                                                                              \
    short8 afr[4][2]; short8 bfr[NFR][2];                                        \
    _Pragma("unroll") for (int m = 0; m < 4; m++)                                \
      _Pragma("unroll") for (int kc = 0; kc < 2; kc++){                          \
        int row = wm * 64 + m * 16 + fr; int slot = (kc * 4 + fq) ^ (row & 7);   \
        afr[m][kc] = *(const short8*)&As[P][row * 64 + slot * 8]; }              \
    _Pragma("unroll") for (int n = 0; n < NFR; n++)                              \
      _Pragma("unroll") for (int kc = 0; kc < 2; kc++){                          \
        int row = wn * (BN / 2) + n * 16 + fr;                                   \
        int slot = (kc * 4 + fq) ^ (row & 7);                                    \
        bfr[n][kc] = *(const short8*)&Bs[P][row * 64 + slot * 8]; }              \
    LGKM0; SBAR();                                                               \
    if ((T) + 1 < KS){                                                           \
      if ((T) + 2 < KS){                                                         \
        _Pragma("unroll") for (int j = 0; j < BLD; j++)                          \
          BRI[j] = *(const float4*)(bS[j] + (size_t)((T) + 2) * 64);             \
        _Pragma("unroll") for (int i = 0; i < 4; i++){ int seg = w * 4 + i;      \
          glds16(aS[i] + (size_t)((T) + 2) * 64, &As[P][seg * 512]); }           \
        if (BLD == 4) { VMW8; } else { VMW6; }                                   \
      } else { VMW0; }                                                           \
      SCHED0;                                                                    \
      _Pragma("unroll") for (int j = 0; j < BLD; j++){                           \
        uint2 pk;                                                                \
        pk.x = (unsigned)f2bf(BRW[j].x) | ((unsigned)f2bf(BRW[j].y) << 16);      \
        pk.y = (unsigned)f2bf(BRW[j].z) | ((unsigned)f2bf(BRW[j].w) << 16);      \
        *(uint2*)&Bs[P ^ 1][bwOff[j]] = pk; }                                    \
      LGKM0; SBAR();                                                             \
    }                                                                            \
    _Pragma("unroll") for (int m = 0; m < 4; m++)                                \
      _Pragma("unroll") for (int n = 0; n < NFR; n++){                           \
        acc[m][n] = __builtin_amdgcn_mfma_f32_16x16x32_bf16(afr[m][0], bfr[n][0], acc[m][n], 0, 0, 0); \
        acc[m][n] = __builtin_amdgcn_mfma_f32_16x16x32_bf16(afr[m][1], bfr[n][1], acc[m][n], 0, 0, 0); \
      }                                                                          \
  }

  for (int t = 0; t < KS; t += 2){
    STEP(0, t,     bregA, bregB)
    STEP(1, t + 1, bregB, bregA)
  }
#undef STEP

  // epilogue: C frag layout col = lane&15, row = (lane>>4)*4 + i
  #pragma unroll
  for (int n = 0; n < NFR; n++){
    int col = n0 + wn * (BN / 2) + n * 16 + fr;
    float bv = bias[(size_t)e * BNTOT + col];
    #pragma unroll
    for (int m = 0; m < 4; m++){
      int rbase = m0 + wm * 64 + m * 16 + fq * 4;
      f32x4 v = acc[m][n];
      #pragma unroll
      for (int i = 0; i < 4; i++){
        int mrow = rbase + i;
        if (mrow < ne){
          int tok = lst[mrow];
          float val = v[i] + bv;
          if (PHASE2){
            yOut[(size_t)tok * DM + col] = gate[tok] * val;
          } else {
            float gl = 0.5f * val * (1.0f + erff(val * 0.70710678118654752f));
            hOut[(size_t)tok * HID + col] = f2bf(gl);
          }
        }
      }
    }
  }
}

extern "C" void kernel_launch(void* const* d_in, const int* in_sizes, int n_in,
                              void* d_out, int out_size, void* d_ws, size_t ws_size,
                              hipStream_t stream) {
  const float* x   = (const float*)d_in[0];
  const float* gw  = (const float*)d_in[1];
  const float* w1  = (const float*)d_in[2];
  const float* b1  = (const float*)d_in[3];
  const float* w2  = (const float*)d_in[4];
  const float* b2  = (const float*)d_in[5];

  char* ws = (char*)d_ws;
  float* gateo = (float*)(ws + GATE_OFF);
  int*   cnt   = (int*)  (ws + CNT_OFF);
  int*   list  = (int*)  (ws + LIST_OFF);
  float* probs = (float*)(ws + PROBS_OFF);
  u16*   xb    = (u16*)  (ws + XB_OFF);
  u16*   h     = (u16*)  (ws + H_OFF);

  float* out = (float*)d_out;
  float* aux = out + (size_t)T_TOK * DM;

  hipLaunchKernelGGL(zero_cnt_kernel, dim3(1), dim3(64), 0, stream, cnt);
  hipLaunchKernelGGL(gate_kernel, dim3(T_TOK / 4), dim3(256), 0, stream,
                     x, gw, gateo, cnt, list, probs, xb);
  hipLaunchKernelGGL(aux_kernel, dim3(1), dim3(256), 0, stream, probs, cnt, aux);

  // GEMM1: xb[tok,1024] x w1[e][4096][1024] -> h[tok][4096]   (BN=128, NT=32)
  hipLaunchKernelGGL((ffn_gemm<128, DM, HID, false>),
                     dim3(NEXP * 16 * (HID / 128)), dim3(512), 0, stream,
                     xb, w1, b1, cnt, list, gateo, h, (float*)nullptr);
  // GEMM2: h[tok,4096] x w2[e][1024][4096] -> out[tok][1024]  (BN=64, NT=16)
  hipLaunchKernelGGL((ffn_gemm<64, HID, DM, true>),
                     dim3(NEXP * 16 * (DM / 64)), dim3(512), 0, stream,
                     h, w2, b2, cnt, list, gateo, (u16*)nullptr, out);
}

// Round 5
// 317.842 us; speedup vs baseline: 1.1876x; 1.1876x over previous
//
#include <hip/hip_runtime.h>
#include <math.h>

#define T_TOK 4096
#define DM 1024
#define HID 4096
#define NEXP 8
#define MAXT 39   // max total 128-row tiles: 4096/128 + 7

typedef unsigned short u16;
typedef __attribute__((ext_vector_type(8))) short short8;
typedef __attribute__((ext_vector_type(4))) float f32x4;

__device__ __forceinline__ u16 f2bf(float f){
  unsigned u = __float_as_uint(f);
  u += 0x7FFF + ((u >> 16) & 1);
  return (u16)(u >> 16);
}

// ---- workspace layout (byte offsets) ---- (verified ws_size >= 176439424)
#define GATE_OFF   0u          // float[4096]
#define CNT_OFF    16384u      // int[8]
#define LIST_OFF   16512u      // int[8][4096]
#define PROBS_OFF  147584u     // float[4096][8]
#define XB_OFF     278656u     // bf16[4096][1024]
#define H_OFF      8667264u    // bf16[4096][4096]
#define W1B_OFF    42221696u   // bf16[8][4096][1024] (dead after GEMM1 -> PART)
#define PART_OFF   W1B_OFF     // float[2][4096][1024] = 32MB
#define W2B_OFF    109330560u  // bf16[8][1024][4096]

__device__ __forceinline__ void glds16(const void* g, void* l){
  __builtin_amdgcn_global_load_lds((const __attribute__((address_space(1))) void*)g,
                                   (__attribute__((address_space(3))) void*)l, 16, 0, 0);
}

#define LGKM0  asm volatile("s_waitcnt lgkmcnt(0)" ::: "memory")
#define VMW6   asm volatile("s_waitcnt vmcnt(6)" ::: "memory")
#define VMW0   asm volatile("s_waitcnt vmcnt(0)" ::: "memory")
#define SBAR() __builtin_amdgcn_s_barrier()

__global__ void zero_cnt_kernel(int* cnt){
  if (threadIdx.x < NEXP) cnt[threadIdx.x] = 0;
}

// fp32 -> bf16 streaming convert, 8 elems/thread
__global__ __launch_bounds__(256) void cvt_kernel(const float* __restrict__ src,
                                                  u16* __restrict__ dst){
  size_t i = (size_t)blockIdx.x * 256 + threadIdx.x;
  const float4* s = (const float4*)src + i * 2;
  float4 a = s[0], b = s[1];
  uint4 p;
  p.x = (unsigned)f2bf(a.x) | ((unsigned)f2bf(a.y) << 16);
  p.y = (unsigned)f2bf(a.z) | ((unsigned)f2bf(a.w) << 16);
  p.z = (unsigned)f2bf(b.x) | ((unsigned)f2bf(b.y) << 16);
  p.w = (unsigned)f2bf(b.z) | ((unsigned)f2bf(b.w) << 16);
  ((uint4*)dst)[i] = p;
}

// one wave per token: gating + routing + x->bf16 conversion
__global__ __launch_bounds__(256) void gate_kernel(
    const float* __restrict__ x, const float* __restrict__ gw,
    float* __restrict__ gateo, int* __restrict__ cnt, int* __restrict__ list,
    float* __restrict__ probs, u16* __restrict__ xb)
{
  int tid = threadIdx.x;
  int lane = tid & 63;
  int w = tid >> 6;
  int t = blockIdx.x * 4 + w;

  const float4* x4 = (const float4*)(x + (size_t)t * DM);
  const float4* g4 = (const float4*)gw;

  float acc[8] = {0,0,0,0,0,0,0,0};
  #pragma unroll
  for (int i = 0; i < 4; i++){
    int p = i * 64 + lane;
    float4 xv = x4[p];
    ushort4 pk;
    pk.x = f2bf(xv.x); pk.y = f2bf(xv.y); pk.z = f2bf(xv.z); pk.w = f2bf(xv.w);
    *(ushort4*)&xb[(size_t)t * DM + (size_t)p * 4] = pk;
    #pragma unroll
    for (int e = 0; e < NEXP; e++){
      float4 gv = g4[e * 256 + p];
      acc[e] += xv.x * gv.x + xv.y * gv.y + xv.z * gv.z + xv.w * gv.w;
    }
  }
  #pragma unroll
  for (int e = 0; e < NEXP; e++){
    #pragma unroll
    for (int off = 32; off; off >>= 1)
      acc[e] += __shfl_xor(acc[e], off);
  }
  if (lane == 0){
    float mx = acc[0];
    #pragma unroll
    for (int e = 1; e < NEXP; e++) mx = fmaxf(mx, acc[e]);
    float p[8]; float s = 0.f;
    #pragma unroll
    for (int e = 0; e < NEXP; e++){ p[e] = expf(acc[e] - mx); s += p[e]; }
    float inv = 1.f / s;
    int be = 0; float bp = p[0];
    #pragma unroll
    for (int e = 1; e < NEXP; e++){ if (p[e] > bp){ bp = p[e]; be = e; } }
    #pragma unroll
    for (int e = 0; e < NEXP; e++) probs[(size_t)t * 8 + e] = p[e] * inv;
    gateo[t] = bp * inv;
    int pos = atomicAdd(&cnt[be], 1);
    list[be * T_TOK + pos] = t;
  }
}

// deterministic aux-loss reduction, one block
__global__ __launch_bounds__(256) void aux_kernel(
    const float* __restrict__ probs, const int* __restrict__ cnt,
    float* __restrict__ aux_out)
{
  __shared__ float sm[256 * 8];
  int tid = threadIdx.x;
  float s[8] = {0,0,0,0,0,0,0,0};
  for (int i = 0; i < 16; i++){
    int t = i * 256 + tid;
    #pragma unroll
    for (int e = 0; e < 8; e++) s[e] += probs[(size_t)t * 8 + e];
  }
  #pragma unroll
  for (int e = 0; e < 8; e++) sm[tid * 8 + e] = s[e];
  __syncthreads();
  for (int st = 128; st; st >>= 1){
    if (tid < st){
      #pragma unroll
      for (int e = 0; e < 8; e++) sm[tid * 8 + e] += sm[(tid + st) * 8 + e];
    }
    __syncthreads();
  }
  if (tid == 0){
    float a = 0.f;
    #pragma unroll
    for (int e = 0; e < 8; e++){
      float f = (float)cnt[e] / (float)T_TOK;
      float P = sm[e] / (float)T_TOK;
      a += f * P;
    }
    aux_out[0] = 0.01f * (float)NEXP * a;
  }
}

// Grouped GEMM, compacted tile grid. BM=128, BN=256, BK=64, 8 waves (2Mx4N).
// Triple-buffered LDS (144KB), glds staging 2 tiles ahead, vmcnt(6) counted.
// bid = (sk*MAXT + t)*NT + nt; block scans cnt[] to decode t -> (e, mt).
// PHASE2=false: A=xb, B=w1b -> h = gelu(acc+b1) bf16
// PHASE2=true : A=h,  B=w2b -> PART[sk][tok][col] = acc (+b2 if sk==0) fp32
template<int KT, int BSTR, int NTOT, int NT, int KS, bool PHASE2>
__global__ __launch_bounds__(512, 2) void ffn_gemm(
    const u16*  __restrict__ Aall,
    const u16*  __restrict__ Bb,
    const float* __restrict__ bias,
    const int*  __restrict__ cnt,
    const int*  __restrict__ list,
    u16*  __restrict__ hOut,
    float* __restrict__ pOut)
{
  int bid = blockIdx.x;
  int nt = bid % NT;
  int r1 = bid / NT;
  int t  = r1 % MAXT;
  int sk = r1 / MAXT;

  // decode compacted tile index -> (e, mt)
  int e = -1, mt = 0, accT = 0;
  #pragma unroll
  for (int i = 0; i < NEXP; i++){
    int nti = (cnt[i] + 127) >> 7;
    if (e < 0 && t < accT + nti){ e = i; mt = t - accT; }
    accT += nti;
  }
  if (e < 0) return;                 // t beyond total tiles
  int ne = cnt[e];
  int m0 = mt * 128;
  const int* lst = list + e * T_TOK;
  int n0 = nt * 256;
  int koff = sk * (KS * 64);

  __shared__ u16 As[3][8192];        // [128][64] swizzled
  __shared__ u16 Bs[3][16384];       // [256][64] swizzled

  int tid  = threadIdx.x;
  int lane = tid & 63;
  int w    = tid >> 6;
  int wm = w >> 2, wn = w & 3;       // 2M x 4N wave grid; wave out 64x64
  int fr = lane & 15, fq = lane >> 4;

  // staging: A = 16 segs of 1KB (2/wave), B = 32 segs (4/wave).
  // lane l -> row seg*8+(l>>3); fetches global chunk g=(l&7)^(row&7) so
  // LDS[row][slot] holds global chunk slot^(row&7) (both-sides swizzle).
  const u16* aS[2]; const u16* bS[4];
  int aDst[2], bDst[4];
  #pragma unroll
  for (int i = 0; i < 2; i++){
    int seg = w * 2 + i;
    int r   = seg * 8 + (lane >> 3);
    int g   = (lane & 7) ^ (r & 7);
    int mrow = m0 + r; if (mrow > ne - 1) mrow = ne - 1;
    aS[i] = Aall + (size_t)lst[mrow] * KT + koff + g * 8;
    aDst[i] = seg * 512;
  }
  #pragma unroll
  for (int i = 0; i < 4; i++){
    int seg = w * 4 + i;
    int r   = seg * 8 + (lane >> 3);
    int g   = (lane & 7) ^ (r & 7);
    bS[i] = Bb + (size_t)e * NTOT * BSTR + (size_t)(n0 + r) * BSTR + koff + g * 8;
    bDst[i] = seg * 512;
  }

  f32x4 acc[4][4];
  #pragma unroll
  for (int m = 0; m < 4; m++)
    #pragma unroll
    for (int n = 0; n < 4; n++)
      acc[m][n] = (f32x4){0.f, 0.f, 0.f, 0.f};

  // prologue: stage tiles 0,1 (6 glds each per wave); wait tile0; barrier.
  #pragma unroll
  for (int i = 0; i < 2; i++) glds16(aS[i],      &As[0][aDst[i]]);
  #pragma unroll
  for (int i = 0; i < 4; i++) glds16(bS[i],      &Bs[0][bDst[i]]);
  #pragma unroll
  for (int i = 0; i < 2; i++) glds16(aS[i] + 64, &As[1][aDst[i]]);
  #pragma unroll
  for (int i = 0; i < 4; i++) glds16(bS[i] + 64, &Bs[1][bDst[i]]);
  VMW6; SBAR();

  for (int ks = 0; ks < KS; ++ks){
    int buf = ks % 3;
    // fragment reads for tile ks
    short8 afr[4][2], bfr[4][2];
    #pragma unroll
    for (int m = 0; m < 4; m++)
      #pragma unroll
      for (int kc = 0; kc < 2; kc++){
        int row = wm * 64 + m * 16 + fr;
        int slot = (kc * 4 + fq) ^ (row & 7);
        afr[m][kc] = *(const short8*)&As[buf][row * 64 + slot * 8];
      }
    #pragma unroll
    for (int n = 0; n < 4; n++)
      #pragma unroll
      for (int kc = 0; kc < 2; kc++){
        int row = wn * 64 + n * 16 + fr;
        int slot = (kc * 4 + fq) ^ (row & 7);
        bfr[n][kc] = *(const short8*)&Bs[buf][row * 64 + slot * 8];
      }
    // stage tile ks+2 into buf (ks+2)%3
    if (ks + 2 < KS){
      int nb = (ks + 2) % 3;
      size_t ko = (size_t)(ks + 2) * 64;
      #pragma unroll
      for (int i = 0; i < 2; i++) glds16(aS[i] + ko, &As[nb][aDst[i]]);
      #pragma unroll
      for (int i = 0; i < 4; i++) glds16(bS[i] + ko, &Bs[nb][bDst[i]]);
      LGKM0;       // own frag reads complete -> regs safe before anyone overwrites
      VMW6;        // oldest 6 (tile ks+1) landed; 6 newest (ks+2) in flight
    } else {
      LGKM0;
      VMW0;        // tail: drain remaining
    }
    SBAR();        // all waves' reads done + tile ks+1 visible everywhere
    // MFMA on registers (overlaps other waves' next-step reads/staging)
    #pragma unroll
    for (int kc = 0; kc < 2; kc++)
      #pragma unroll
      for (int m = 0; m < 4; m++)
        #pragma unroll
        for (int n = 0; n < 4; n++)
          acc[m][n] = __builtin_amdgcn_mfma_f32_16x16x32_bf16(afr[m][kc], bfr[n][kc], acc[m][n], 0, 0, 0);
  }

  // epilogue: C frag layout col = lane&15, row = (lane>>4)*4 + i
  #pragma unroll
  for (int n = 0; n < 4; n++){
    int col = n0 + wn * 64 + n * 16 + fr;
    float bv = bias[(size_t)e * NTOT + col];
    if (PHASE2 && (r1 / MAXT) != 0) bv = 0.f;
    #pragma unroll
    for (int m = 0; m < 4; m++){
      int rbase = m0 + wm * 64 + m * 16 + fq * 4;
      f32x4 v = acc[m][n];
      #pragma unroll
      for (int i = 0; i < 4; i++){
        int mrow = rbase + i;
        if (mrow < ne){
          int tok = lst[mrow];
          float val = v[i] + bv;
          if (PHASE2){
            pOut[((size_t)sk * T_TOK + tok) * DM + col] = val;
          } else {
            float gl = 0.5f * val * (1.0f + erff(val * 0.70710678118654752f));
            hOut[(size_t)tok * HID + col] = f2bf(gl);
          }
        }
      }
    }
  }
}

// out = gate * (part0 + part1 (+b2 already in part0))
__global__ __launch_bounds__(256) void reduce_kernel(
    const float* __restrict__ part, const float* __restrict__ gate,
    float* __restrict__ out)
{
  size_t i = (size_t)blockIdx.x * 256 + threadIdx.x;     // float4 index
  constexpr size_t S = (size_t)T_TOK * DM / 4;
  const float4* p = (const float4*)part;
  float4 a = p[i], b = p[i + S];
  float g = gate[i >> 8];                                // 256 float4 per row
  float4 o;
  o.x = (a.x + b.x) * g;
  o.y = (a.y + b.y) * g;
  o.z = (a.z + b.z) * g;
  o.w = (a.w + b.w) * g;
  ((float4*)out)[i] = o;
}

extern "C" void kernel_launch(void* const* d_in, const int* in_sizes, int n_in,
                              void* d_out, int out_size, void* d_ws, size_t ws_size,
                              hipStream_t stream) {
  const float* x   = (const float*)d_in[0];
  const float* gw  = (const float*)d_in[1];
  const float* w1  = (const float*)d_in[2];
  const float* b1  = (const float*)d_in[3];
  const float* w2  = (const float*)d_in[4];
  const float* b2  = (const float*)d_in[5];

  char* ws = (char*)d_ws;
  float* gateo = (float*)(ws + GATE_OFF);
  int*   cnt   = (int*)  (ws + CNT_OFF);
  int*   list  = (int*)  (ws + LIST_OFF);
  float* probs = (float*)(ws + PROBS_OFF);
  u16*   xb    = (u16*)  (ws + XB_OFF);
  u16*   h     = (u16*)  (ws + H_OFF);
  u16*   w1b   = (u16*)  (ws + W1B_OFF);
  float* part  = (float*)(ws + PART_OFF);   // overlays w1b (dead after GEMM1)
  u16*   w2b   = (u16*)  (ws + W2B_OFF);

  float* out = (float*)d_out;
  float* aux = out + (size_t)T_TOK * DM;

  hipLaunchKernelGGL(zero_cnt_kernel, dim3(1), dim3(64), 0, stream, cnt);
  hipLaunchKernelGGL(gate_kernel, dim3(T_TOK / 4), dim3(256), 0, stream,
                     x, gw, gateo, cnt, list, probs, xb);
  hipLaunchKernelGGL(aux_kernel, dim3(1), dim3(256), 0, stream, probs, cnt, aux);
  hipLaunchKernelGGL(cvt_kernel, dim3(16384), dim3(256), 0, stream, w1, w1b);
  hipLaunchKernelGGL(cvt_kernel, dim3(16384), dim3(256), 0, stream, w2, w2b);

  // GEMM1: xb[tok,1024] x w1b[e][4096][1024] -> h[tok][4096]
  //   KT=1024, BSTR=1024, NTOT=4096, NT=16, KS=16, grid = MAXT*16 = 624
  hipLaunchKernelGGL((ffn_gemm<DM, DM, HID, 16, 16, false>),
                     dim3(MAXT * 16), dim3(512), 0, stream,
                     xb, w1b, b1, cnt, list, h, (float*)nullptr);
  // GEMM2: h[tok,4096] x w2b[e][1024][4096] -> PART[sk][tok][1024], split-K=2
  //   KT=4096, BSTR=4096, NTOT=1024, NT=4, KS=32, grid = 2*MAXT*4 = 312
  hipLaunchKernelGGL((ffn_gemm<HID, HID, DM, 4, 32, true>),
                     dim3(2 * MAXT * 4), dim3(512), 0, stream,
                     h, w2b, b2, cnt, list, (u16*)nullptr, part);
  hipLaunchKernelGGL(reduce_kernel, dim3(T_TOK * DM / 4 / 256), dim3(256), 0, stream,
                     part, gateo, out);
}